// Round 4
// baseline (131.541 us; speedup 1.0000x reference)
//
#include <hip/hip_runtime.h>

// ContrastiveLoss on MI355X (gfx950) — round 8 (= R7 resubmit after infra flake)
// loss = (1/n) [ sum_i P_i*(10+log z_i) - 10*(sum_c ||S_c||^2 - n) ]
//   z_i = sum_{j != i} exp(10*dot_ij - 10)
//   S_c = sum_{label_j == c} e_j   (exact fp32 via rowlist gather)
// R7/R8: (a) prep's 1M memory-side fp32 atomics (~13us) replaced by enorm
// write + one rowlist append per row (8K atomics); 100-block classsum
// gathers ~82 rows/class coalesced -> exact S_c, no partials.
// (b) zsum stages the full 256-row B-window (64KB bf16) in LDS ONCE
// (single barrier), then a barrier-free ds_read_b128 + MFMA loop — removes
// in-loop L2 latency and the 4x per-wave B duplication.
// R8 delta vs R7: defensive clamp on rowlist slot (only data-dependent
// store index in the pipeline); unused var removed. Logic unchanged.

#define N 8192
#define D 128
#define NCLS 100
#define RLCAP 256          // rowlist slots per class (~82+-9 expected; huge margin)
#define JSPLIT 32          // grid.y; j-window = 256 rows (64 KB bf16 in LDS)
#define IBLK 256           // i-rows per block (4 waves x 64)
#define NJT ((N / JSPLIT) / 16)
#define K2E 14.4269504088896340736f   // 10*log2(e)
#define LN2 0.69314718055994530942f

typedef __bf16 bf16x8 __attribute__((ext_vector_type(8)));
typedef float f32x4 __attribute__((ext_vector_type(4)));

// ws layout (bytes) — CNT and Z contiguous so one memset zeroes both
#define EBF_OFF  0x000000u  // bf16 E fragment-major: 2 MB
#define ENORM_OFF 0x200000u // fp32 normalized E row-major: 4 MB
#define CNT_OFF  0x600000u  // class counts: 512 B
#define Z_OFF    0x600200u  // z per row: 32 KB
#define RL_OFF   0x608200u  // rowlist: 100*256*4 = 100 KB (gated by cnt, no init)
#define S_OFF    0x621200u  // S_c: 100*128*4 = 50 KB (fully written)
#define ZERO_SZ  (512u + 32768u)

__device__ __forceinline__ unsigned short f32_to_bf16_rne(float f) {
    unsigned int u = __float_as_uint(f);
    u += 0x7fffu + ((u >> 16) & 1u);
    return (unsigned short)(u >> 16);
}

// Fragment-major layout of E (harness-verified):
//   row r: grp=r>>4, col=r&15 ; element k: c=k>>5, q=(k>>3)&3, jj=k&7
//   byte = grp*4096 + c*1024 + q*256 + col*16 + jj*2

// Kernel 1: normalize rows -> fragment-major bf16 E + row-major fp32 enorm;
// class histogram doubles as rowlist slot allocator (1 atomic per row).
__global__ __launch_bounds__(256) void prep_kernel(
        const float* __restrict__ emb, const int* __restrict__ labels,
        unsigned char* __restrict__ ebf, int* __restrict__ cnt,
        float* __restrict__ enorm, int* __restrict__ rowlist) {
    const int wave = threadIdx.x >> 6;
    const int lane = threadIdx.x & 63;
    const int row  = blockIdx.x * 4 + wave;

    const float2 v = *(const float2*)(emb + (size_t)row * D + lane * 2);
    float ss = v.x * v.x + v.y * v.y;
    #pragma unroll
    for (int off = 32; off; off >>= 1) ss += __shfl_xor(ss, off);
    const float inv = 1.0f / fmaxf(sqrtf(ss), 1e-12f);
    const float ex = v.x * inv, ey = v.y * inv;

    const int grp = row >> 4, col = row & 15;
    const int c = lane >> 4, q = (lane >> 2) & 3, j2 = lane & 3;
    unsigned int packed = (unsigned int)f32_to_bf16_rne(ex) |
                          ((unsigned int)f32_to_bf16_rne(ey) << 16);
    *(unsigned int*)(ebf + grp * 4096 + c * 1024 + q * 256 + col * 16 + j2 * 4) = packed;

    float2* ep = (float2*)(enorm + (size_t)row * D + lane * 2);
    *ep = make_float2(ex, ey);

    if (lane == 0) {
        const int lab = labels[row];
        int slot = atomicAdd(&cnt[lab], 1);
        slot = slot < RLCAP ? slot : RLCAP - 1;   // defensive (never hit @ ~82/class)
        rowlist[lab * RLCAP + slot] = row;
    }
}

// Kernel 2: exact fp32 per-class sums via rowlist gather.
// 100 blocks x 128 threads; thread owns one dim; ~82 coalesced row reads.
__global__ __launch_bounds__(128) void classsum_kernel(
        const float* __restrict__ enorm, const int* __restrict__ cnt,
        const int* __restrict__ rowlist, float* __restrict__ S) {
    const int c = blockIdx.x;
    const int d = threadIdx.x;
    const int n = cnt[c] < RLCAP ? cnt[c] : RLCAP;
    const int* rl = rowlist + c * RLCAP;
    float acc = 0.0f;
    int idx = 0;
    for (; idx + 4 <= n; idx += 4) {
        const int r0 = rl[idx], r1 = rl[idx + 1], r2 = rl[idx + 2], r3 = rl[idx + 3];
        const float v0 = enorm[(size_t)r0 * D + d];
        const float v1 = enorm[(size_t)r1 * D + d];
        const float v2 = enorm[(size_t)r2 * D + d];
        const float v3 = enorm[(size_t)r3 * D + d];
        acc += v0 + v1 + v2 + v3;
    }
    for (; idx < n; ++idx)
        acc += enorm[(size_t)rl[idx] * D + d];
    S[c * D + d] = acc;
}

// Kernel 3: z only. Block = 4 waves; wave owns 64 i-rows (4 groups of 16).
// grid (N/IBLK, JSPLIT). B-window (64 KB) staged in LDS once, single
// barrier, then barrier-free ds_read_b128 + MFMA + exp loop.
__global__ __launch_bounds__(256) void zsum_kernel(
        const unsigned char* __restrict__ ebf, float* __restrict__ z) {
    __shared__ unsigned char blds[64 * 1024];
    const int t    = threadIdx.x;
    const int w    = t >> 6;
    const int lane = t & 63;
    const int q    = lane >> 4;
    const int col  = lane & 15;
    const int iw   = blockIdx.x * IBLK + w * 64;
    const int jb   = blockIdx.y * (N / JSPLIT);

    // stage B window: 64 chunks of 1KB; wave w stages chunks [w*16, w*16+16)
    const unsigned char* bsrc = ebf + (size_t)(jb >> 4) * 4096 + lane * 16;
    #pragma unroll 1
    for (int kb = 0; kb < 4; ++kb) {
        bf16x8 tmp[4];
        #pragma unroll
        for (int u = 0; u < 4; ++u)
            tmp[u] = *(const bf16x8*)(bsrc + (size_t)(w * 16 + kb * 4 + u) * 1024);
        #pragma unroll
        for (int u = 0; u < 4; ++u)
            *(bf16x8*)(blds + (w * 16 + kb * 4 + u) * 1024 + lane * 16) = tmp[u];
    }

    // A fragments: 4 groups x 4 K-chunks, coalesced 1KB loads (overlap barrier)
    bf16x8 a[4][4];
    #pragma unroll
    for (int g = 0; g < 4; ++g) {
        const unsigned char* ag = ebf + (size_t)(iw / 16 + g) * 4096 + lane * 16;
        #pragma unroll
        for (int c = 0; c < 4; ++c) a[g][c] = *(const bf16x8*)(ag + c * 1024);
    }

    __syncthreads();

    float zacc[4][4] = {{0.f,0.f,0.f,0.f},{0.f,0.f,0.f,0.f},
                        {0.f,0.f,0.f,0.f},{0.f,0.f,0.f,0.f}};

    #pragma unroll 2
    for (int jt = 0; jt < NJT; ++jt) {
        const int js = jb + jt * 16;
        bf16x8 b[4];
        #pragma unroll
        for (int c = 0; c < 4; ++c)
            b[c] = *(const bf16x8*)(blds + (jt * 4 + c) * 1024 + lane * 16);

        #pragma unroll
        for (int g = 0; g < 4; ++g) {
            f32x4 acc = {0.f, 0.f, 0.f, 0.f};
            __builtin_amdgcn_s_setprio(1);
            #pragma unroll
            for (int c = 0; c < 4; ++c)
                acc = __builtin_amdgcn_mfma_f32_16x16x32_bf16(a[g][c], b[c], acc, 0, 0, 0);
            __builtin_amdgcn_s_setprio(0);
            if (js == iw + g * 16) {                  // wave-uniform diagonal tile
                #pragma unroll
                for (int r = 0; r < 4; ++r)
                    zacc[g][r] += (col == q * 4 + r) ? 0.0f
                        : __builtin_amdgcn_exp2f(fmaf(acc[r], K2E, -K2E));
            } else {
                #pragma unroll
                for (int r = 0; r < 4; ++r)
                    zacc[g][r] += __builtin_amdgcn_exp2f(fmaf(acc[r], K2E, -K2E));
            }
        }
    }

    // per-row reduce across the 16 cols of each quad; atomic merge of partials
    #pragma unroll
    for (int g = 0; g < 4; ++g)
        #pragma unroll
        for (int r = 0; r < 4; ++r) {
            float zv = zacc[g][r];
            zv += __shfl_xor(zv, 1);
            zv += __shfl_xor(zv, 2);
            zv += __shfl_xor(zv, 4);
            zv += __shfl_xor(zv, 8);
            if (col == 0)
                atomicAdd(&z[iw + g * 16 + q * 4 + r], zv);
        }
}

// Kernel 4: single-block epilogue.
// loss = [ sum_i P_i*(10+ln z_i) - 10*sum_k S[k]^2 + 10*N ] / N
__global__ __launch_bounds__(1024) void final_kernel(
        const int* __restrict__ labels, const int* __restrict__ cnt,
        const float* __restrict__ z, const float* __restrict__ S,
        float* __restrict__ out) {
    __shared__ float part[16];
    const int tid = threadIdx.x;
    float acc = 0.0f;
    #pragma unroll
    for (int k = 0; k < N / 1024; ++k) {
        const int row = k * 1024 + tid;
        const int P = cnt[labels[row]] - 1;
        if (P > 0)
            acc += (float)P * fmaf(LN2, __builtin_amdgcn_logf(z[row]), 10.0f);
    }
    #pragma unroll
    for (int k = 0; k < (NCLS * D + 1023) / 1024; ++k) {
        const int idx = k * 1024 + tid;
        if (idx < NCLS * D) {
            const float sv = S[idx];
            acc -= 10.0f * sv * sv;
        }
    }
    #pragma unroll
    for (int off = 32; off; off >>= 1) acc += __shfl_xor(acc, off);
    if ((tid & 63) == 0) part[tid >> 6] = acc;
    __syncthreads();
    if (tid == 0) {
        float tot = 0.0f;
        #pragma unroll
        for (int w = 0; w < 16; ++w) tot += part[w];
        out[0] = (tot + 10.0f * (float)N) * (1.0f / (float)N);
    }
}

extern "C" void kernel_launch(void* const* d_in, const int* in_sizes, int n_in,
                              void* d_out, int out_size, void* d_ws, size_t ws_size,
                              hipStream_t stream) {
    const float* emb  = (const float*)d_in[0];
    const int* labels = (const int*)d_in[1];
    float* out        = (float*)d_out;
    char* ws          = (char*)d_ws;

    unsigned char* ebf = (unsigned char*)(ws + EBF_OFF);
    float* enorm       = (float*)(ws + ENORM_OFF);
    int*   cnt         = (int*)(ws + CNT_OFF);
    float* z           = (float*)(ws + Z_OFF);
    int*   rowlist     = (int*)(ws + RL_OFF);
    float* S           = (float*)(ws + S_OFF);

    hipMemsetAsync(ws + CNT_OFF, 0, ZERO_SZ, stream);

    prep_kernel<<<N / 4, 256, 0, stream>>>(emb, labels, ebf, cnt, enorm, rowlist);
    classsum_kernel<<<NCLS, 128, 0, stream>>>(enorm, cnt, rowlist, S);
    zsum_kernel<<<dim3(N / IBLK, JSPLIT), 256, 0, stream>>>(ebf, z);
    final_kernel<<<1, 1024, 0, stream>>>(labels, cnt, z, S, out);
}

// Round 5
// 127.143 us; speedup vs baseline: 1.0346x; 1.0346x over previous
//
#include <hip/hip_runtime.h>

// ContrastiveLoss on MI355X (gfx950) — round 9
// loss = (1/n) [ sum_i P_i*(10+log z_i) - 10*(sum_c ||S_c||^2 - n) ]
//   z_i = sum_{j != i} exp(10*dot_ij - 10)
//   S_c = sum_{label_j == c} e_j   (exact fp32 via rowlist gather)
// R9: zsum REVERTED to the R6 register-double-buffer/no-LDS/no-barrier form.
// R8's one-shot 64KB LDS staging capped residency at 2 blocks/CU (2 waves/
// SIMD) and cost ~15us of exposed MFMA/exp2/load latency — B is L2-resident,
// so occupancy beats LDS reuse. prep/classsum/final keep the R8 structure
// (rowlist gather instead of 1M memory-side atomics).

#define N 8192
#define D 128
#define NCLS 100
#define RLCAP 256          // rowlist slots per class (~82+-9 expected; huge margin)
#define JSPLIT 32          // grid.y; j-window = 256 rows
#define IBLK 256           // i-rows per block (4 waves x 64)
#define NJT ((N / JSPLIT) / 16)
#define K2E 14.4269504088896340736f   // 10*log2(e)
#define LN2 0.69314718055994530942f

typedef __bf16 bf16x8 __attribute__((ext_vector_type(8)));
typedef float f32x4 __attribute__((ext_vector_type(4)));

// ws layout (bytes) — CNT and Z contiguous so one memset zeroes both
#define EBF_OFF  0x000000u  // bf16 E fragment-major: 2 MB
#define ENORM_OFF 0x200000u // fp32 normalized E row-major: 4 MB
#define CNT_OFF  0x600000u  // class counts: 512 B
#define Z_OFF    0x600200u  // z per row: 32 KB
#define RL_OFF   0x608200u  // rowlist: 100*256*4 = 100 KB (gated by cnt, no init)
#define S_OFF    0x621200u  // S_c: 100*128*4 = 50 KB (fully written)
#define ZERO_SZ  (512u + 32768u)

__device__ __forceinline__ unsigned short f32_to_bf16_rne(float f) {
    unsigned int u = __float_as_uint(f);
    u += 0x7fffu + ((u >> 16) & 1u);
    return (unsigned short)(u >> 16);
}

// Fragment-major layout of E (harness-verified):
//   row r: grp=r>>4, col=r&15 ; element k: c=k>>5, q=(k>>3)&3, jj=k&7
//   byte = grp*4096 + c*1024 + q*256 + col*16 + jj*2

// Kernel 1: normalize rows -> fragment-major bf16 E + row-major fp32 enorm;
// class histogram doubles as rowlist slot allocator (1 atomic per row).
__global__ __launch_bounds__(256) void prep_kernel(
        const float* __restrict__ emb, const int* __restrict__ labels,
        unsigned char* __restrict__ ebf, int* __restrict__ cnt,
        float* __restrict__ enorm, int* __restrict__ rowlist) {
    const int wave = threadIdx.x >> 6;
    const int lane = threadIdx.x & 63;
    const int row  = blockIdx.x * 4 + wave;

    const float2 v = *(const float2*)(emb + (size_t)row * D + lane * 2);
    float ss = v.x * v.x + v.y * v.y;
    #pragma unroll
    for (int off = 32; off; off >>= 1) ss += __shfl_xor(ss, off);
    const float inv = 1.0f / fmaxf(sqrtf(ss), 1e-12f);
    const float ex = v.x * inv, ey = v.y * inv;

    const int grp = row >> 4, col = row & 15;
    const int c = lane >> 4, q = (lane >> 2) & 3, j2 = lane & 3;
    unsigned int packed = (unsigned int)f32_to_bf16_rne(ex) |
                          ((unsigned int)f32_to_bf16_rne(ey) << 16);
    *(unsigned int*)(ebf + grp * 4096 + c * 1024 + q * 256 + col * 16 + j2 * 4) = packed;

    float2* ep = (float2*)(enorm + (size_t)row * D + lane * 2);
    *ep = make_float2(ex, ey);

    if (lane == 0) {
        const int lab = labels[row];
        int slot = atomicAdd(&cnt[lab], 1);
        slot = slot < RLCAP ? slot : RLCAP - 1;   // defensive (never hit @ ~82/class)
        rowlist[lab * RLCAP + slot] = row;
    }
}

// Kernel 2: exact fp32 per-class sums via rowlist gather.
// 100 blocks x 128 threads; thread owns one dim; ~82 coalesced row reads.
__global__ __launch_bounds__(128) void classsum_kernel(
        const float* __restrict__ enorm, const int* __restrict__ cnt,
        const int* __restrict__ rowlist, float* __restrict__ S) {
    const int c = blockIdx.x;
    const int d = threadIdx.x;
    const int n = cnt[c] < RLCAP ? cnt[c] : RLCAP;
    const int* rl = rowlist + c * RLCAP;
    float acc = 0.0f;
    int idx = 0;
    for (; idx + 4 <= n; idx += 4) {
        const int r0 = rl[idx], r1 = rl[idx + 1], r2 = rl[idx + 2], r3 = rl[idx + 3];
        const float v0 = enorm[(size_t)r0 * D + d];
        const float v1 = enorm[(size_t)r1 * D + d];
        const float v2 = enorm[(size_t)r2 * D + d];
        const float v3 = enorm[(size_t)r3 * D + d];
        acc += v0 + v1 + v2 + v3;
    }
    for (; idx < n; ++idx)
        acc += enorm[(size_t)rl[idx] * D + d];
    S[c * D + d] = acc;
}

// Kernel 3: z only. Block = 4 waves; wave owns 64 i-rows (4 groups of 16).
// grid (N/IBLK, JSPLIT). No LDS, no barriers, no labels. B double-buffered
// in registers: next tile's 4x1KB loads issue before current tile's MFMAs.
__global__ __launch_bounds__(256) void zsum_kernel(
        const unsigned char* __restrict__ ebf, float* __restrict__ z) {
    const int t    = threadIdx.x;
    const int w    = t >> 6;
    const int lane = t & 63;
    const int q    = lane >> 4;
    const int col  = lane & 15;
    const int iw   = blockIdx.x * IBLK + w * 64;
    const int jb   = blockIdx.y * (N / JSPLIT);

    // A fragments: 4 groups x 4 K-chunks, coalesced 1KB loads
    bf16x8 a[4][4];
    #pragma unroll
    for (int g = 0; g < 4; ++g) {
        const unsigned char* ag = ebf + (size_t)(iw / 16 + g) * 4096 + lane * 16;
        #pragma unroll
        for (int c = 0; c < 4; ++c) a[g][c] = *(const bf16x8*)(ag + c * 1024);
    }

    float zacc[4][4] = {{0.f,0.f,0.f,0.f},{0.f,0.f,0.f,0.f},
                        {0.f,0.f,0.f,0.f},{0.f,0.f,0.f,0.f}};

    const unsigned char* bbase = ebf + (size_t)(jb / 16) * 4096 + lane * 16;

    // prologue: load B tile 0
    bf16x8 bc[4];
    #pragma unroll
    for (int c = 0; c < 4; ++c) bc[c] = *(const bf16x8*)(bbase + c * 1024);

    #pragma unroll 2
    for (int jt = 0; jt < NJT; ++jt) {
        const int js = jb + jt * 16;

        // prefetch next B tile (last iter reloads current — harmless, defined)
        const int jn = (jt + 1 < NJT) ? jt + 1 : jt;
        bf16x8 bn[4];
        {
            const unsigned char* bg = bbase + (size_t)jn * 4096;
            #pragma unroll
            for (int c = 0; c < 4; ++c) bn[c] = *(const bf16x8*)(bg + c * 1024);
        }

        #pragma unroll
        for (int g = 0; g < 4; ++g) {
            f32x4 acc = {0.f, 0.f, 0.f, 0.f};
            __builtin_amdgcn_s_setprio(1);
            #pragma unroll
            for (int c = 0; c < 4; ++c)
                acc = __builtin_amdgcn_mfma_f32_16x16x32_bf16(a[g][c], bc[c], acc, 0, 0, 0);
            __builtin_amdgcn_s_setprio(0);
            if (js == iw + g * 16) {                  // wave-uniform diagonal tile
                #pragma unroll
                for (int r = 0; r < 4; ++r)
                    zacc[g][r] += (col == q * 4 + r) ? 0.0f
                        : __builtin_amdgcn_exp2f(fmaf(acc[r], K2E, -K2E));
            } else {
                #pragma unroll
                for (int r = 0; r < 4; ++r)
                    zacc[g][r] += __builtin_amdgcn_exp2f(fmaf(acc[r], K2E, -K2E));
            }
        }

        #pragma unroll
        for (int c = 0; c < 4; ++c) bc[c] = bn[c];
    }

    // per-row reduce across the 16 cols of each quad; atomic merge of partials
    #pragma unroll
    for (int g = 0; g < 4; ++g)
        #pragma unroll
        for (int r = 0; r < 4; ++r) {
            float zv = zacc[g][r];
            zv += __shfl_xor(zv, 1);
            zv += __shfl_xor(zv, 2);
            zv += __shfl_xor(zv, 4);
            zv += __shfl_xor(zv, 8);
            if (col == 0)
                atomicAdd(&z[iw + g * 16 + q * 4 + r], zv);
        }
}

// Kernel 4: single-block epilogue.
// loss = [ sum_i P_i*(10+ln z_i) - 10*sum_k S[k]^2 + 10*N ] / N
__global__ __launch_bounds__(1024) void final_kernel(
        const int* __restrict__ labels, const int* __restrict__ cnt,
        const float* __restrict__ z, const float* __restrict__ S,
        float* __restrict__ out) {
    __shared__ float part[16];
    const int tid = threadIdx.x;
    float acc = 0.0f;
    #pragma unroll
    for (int k = 0; k < N / 1024; ++k) {
        const int row = k * 1024 + tid;
        const int P = cnt[labels[row]] - 1;
        if (P > 0)
            acc += (float)P * fmaf(LN2, __builtin_amdgcn_logf(z[row]), 10.0f);
    }
    #pragma unroll
    for (int k = 0; k < (NCLS * D + 1023) / 1024; ++k) {
        const int idx = k * 1024 + tid;
        if (idx < NCLS * D) {
            const float sv = S[idx];
            acc -= 10.0f * sv * sv;
        }
    }
    #pragma unroll
    for (int off = 32; off; off >>= 1) acc += __shfl_xor(acc, off);
    if ((tid & 63) == 0) part[tid >> 6] = acc;
    __syncthreads();
    if (tid == 0) {
        float tot = 0.0f;
        #pragma unroll
        for (int w = 0; w < 16; ++w) tot += part[w];
        out[0] = (tot + 10.0f * (float)N) * (1.0f / (float)N);
    }
}

extern "C" void kernel_launch(void* const* d_in, const int* in_sizes, int n_in,
                              void* d_out, int out_size, void* d_ws, size_t ws_size,
                              hipStream_t stream) {
    const float* emb  = (const float*)d_in[0];
    const int* labels = (const int*)d_in[1];
    float* out        = (float*)d_out;
    char* ws          = (char*)d_ws;

    unsigned char* ebf = (unsigned char*)(ws + EBF_OFF);
    float* enorm       = (float*)(ws + ENORM_OFF);
    int*   cnt         = (int*)(ws + CNT_OFF);
    float* z           = (float*)(ws + Z_OFF);
    int*   rowlist     = (int*)(ws + RL_OFF);
    float* S           = (float*)(ws + S_OFF);

    hipMemsetAsync(ws + CNT_OFF, 0, ZERO_SZ, stream);

    prep_kernel<<<N / 4, 256, 0, stream>>>(emb, labels, ebf, cnt, enorm, rowlist);
    classsum_kernel<<<NCLS, 128, 0, stream>>>(enorm, cnt, rowlist, S);
    zsum_kernel<<<dim3(N / IBLK, JSPLIT), 256, 0, stream>>>(ebf, z);
    final_kernel<<<1, 1024, 0, stream>>>(labels, cnt, z, S, out);
}